// Round 7
// baseline (124.970 us; speedup 1.0000x reference)
//
#include <hip/hip_runtime.h>
#include <math.h>

#define KK 64
#define DD 256
#define GX 256        // blocks per feature; grid = 512 blocks = 2/CU
#define MT 16         // rows per wave-microtile
#define MAXCHUNK 512  // max rows per block (N <= GX*MAXCHUNK)
#define INV_TAU 2.0f
#define EPSL 1e-8f

typedef __attribute__((address_space(1))) const void gvoid;
typedef __attribute__((address_space(3))) void svoid;

// ws float layout:
// P : [2][GX][K*D]   per-block partial sums (33.5 MB)
// C : [2][GX][K]     per-block partial counts
// AR: [2][K*D]       normalized prototypes
// lossk: [K]

__global__ __launch_bounds__(512, 4) void seg_partial_kernel(
    const float* __restrict__ fa, const float* __restrict__ fr,
    const int* __restrict__ la, const int* __restrict__ lr,
    float* __restrict__ P, float* __restrict__ C, int N)
{
    // 8 waves x 2 bufs x (16 rows x 64 cols) = 64 KB, wave-private stages
    __shared__ __attribute__((aligned(16))) float stg[8][2][MT * 64];
    __shared__ int lbl[MAXCHUNK];
    __shared__ int cnt[KK];

    const int tid = threadIdx.x;
    const int g = blockIdx.x, f = blockIdx.y;
    const float* __restrict__ feat = f ? fr : fa;
    const int* __restrict__ label = f ? lr : la;

    if (tid < KK) cnt[tid] = 0;

    const int chunk = (N + GX - 1) / GX;
    const int n0 = g * chunk;
    int rows = min(N, n0 + chunk) - n0;
    if (rows < 0) rows = 0;

    __syncthreads();
    for (int i = tid; i < rows; i += 512) lbl[i] = label[n0 + i];
    __syncthreads();
    for (int i = tid; i < rows; i += 512) atomicAdd(&cnt[lbl[i]], 1); // off hot path

    const int w = tid >> 6, lane = tid & 63;
    const int q = w & 3;          // column quarter: columns [64q, 64q+64)
    const int s = w >> 2;         // row-slice: microtiles j ≡ s (mod 2)
    const int col0 = q * 64;

    // per-wave accumulator: lane owns column col0+lane for all 64 classes.
    // statically indexed via unrolled k loop -> VGPRs.
    float accr[KK];
    #pragma unroll
    for (int k = 0; k < KK; ++k) accr[k] = 0.0f;

    // stage microtile j's column-slice into private buffer b:
    // 16 x global_load_lds width 4 (256 B coalesced each), dest lane-linear.
    #define STAGEW(j, b)                                                        \
    do {                                                                        \
        const int base_ = (j) * MT;                                             \
        float* lb_ = &stg[w][b][0];                                             \
        _Pragma("unroll")                                                       \
        for (int i_ = 0; i_ < MT; ++i_) {                                       \
            const int row_ = n0 + base_ + i_;                                   \
            size_t e_ = (size_t)row_ * DD + col0 + lane;                        \
            if (row_ >= N) e_ = 0;  /* clamp OOB on tail */                     \
            __builtin_amdgcn_global_load_lds((gvoid*)(feat + e_),               \
                                             (svoid*)(lb_ + i_ * 64), 4, 0, 0);\
        }                                                                       \
    } while (0)

    const int nmt = (rows + MT - 1) / MT;
    int pb = 0;
    if (s < nmt) STAGEW(s, 0);
    for (int j = s; j < nmt; j += 2) {
        const int jn = j + 2;
        if (jn < nmt) {
            STAGEW(jn, pb ^ 1);
            asm volatile("s_waitcnt vmcnt(16)" ::: "memory"); // microtile j landed
        } else {
            asm volatile("s_waitcnt vmcnt(0)" ::: "memory");
        }

        const int base = j * MT;
        const int idx = base + lane;
        const int myl = (lane < MT && idx < rows) ? lbl[idx] : -1;
        const float* sb = &stg[w][pb][0];

        #pragma unroll
        for (int k = 0; k < KK; ++k) {
            unsigned long long m = __ballot(myl == k);   // wave-private mask
            while (m) {
                const int r = (int)__builtin_ctzll(m);
                m &= m - 1;
                accr[k] += sb[r * 64 + lane];            // ds_read_b32, 2-way free
            }
        }
        pb ^= 1;
    }
    #undef STAGEW

    // combine the two row-slice waves per column-quarter through LDS
    __syncthreads();                       // all pops done; stg reusable; cnt final
    float* sf = (float*)stg;               // 16384 floats
    if (s == 1) {
        #pragma unroll
        for (int k = 0; k < KK; ++k) sf[q * 4096 + k * 64 + lane] = accr[k];
    }
    __syncthreads();
    if (s == 0) {
        float* dstb = P + ((size_t)f * GX + g) * (KK * DD);
        #pragma unroll
        for (int k = 0; k < KK; ++k) {
            const float v = accr[k] + sf[q * 4096 + k * 64 + lane];
            dstb[(size_t)k * DD + col0 + lane] = v;      // 256 B coalesced per k
        }
    }
    if (tid < KK) C[((size_t)f * GX + g) * KK + tid] = (float)cnt[tid];
}

__global__ __launch_bounds__(256) void proto_norm_kernel(
    const float* __restrict__ P, const float* __restrict__ C,
    float* __restrict__ AR, int G)
{
    const int k = blockIdx.x, f = blockIdx.y, tid = threadIdx.x;
    const float* base = P + (size_t)f * G * (KK * DD) + (size_t)k * DD + tid;

    float s = 0.0f;
    int g = 0;
    for (; g + 8 <= G; g += 8) {
        float v[8];
        #pragma unroll
        for (int u = 0; u < 8; ++u) v[u] = base[(size_t)(g + u) * (KK * DD)];
        #pragma unroll
        for (int u = 0; u < 8; ++u) s += v[u];
    }
    for (; g < G; ++g) s += base[(size_t)g * (KK * DD)];

    float c = 0.0f;
    const float* cb = C + (size_t)f * G * KK + k;
    for (int g2 = 0; g2 < G; ++g2) c += cb[(size_t)g2 * KK];

    const float m = s / c;
    float sq = m * m;
    #pragma unroll
    for (int i = 1; i < 64; i <<= 1) sq += __shfl_xor(sq, i, 64);
    __shared__ float red[4];
    const int wid = tid >> 6, lane = tid & 63;
    if (lane == 0) red[wid] = sq;
    __syncthreads();
    const float nrm = red[0] + red[1] + red[2] + red[3];
    AR[(size_t)f * KK * DD + (size_t)k * DD + tid] = m / fmaxf(sqrtf(nrm), 1e-12f);
}

__global__ __launch_bounds__(256) void loss_kernel(const float* __restrict__ AR,
                                                   float* __restrict__ lossk)
{
    const float* A = AR;
    const float* R = AR + KK * DD;
    const int k = blockIdx.x, tid = threadIdx.x;

    const float a = A[k * DD + tid];
    const float r = R[k * DD + tid];
    const float lfp = a * r * INV_TAU;
    const float fp = expf(lfp);
    float ssa = 0.0f, ssr = 0.0f;
    #pragma unroll 8
    for (int j = 0; j < KK; ++j) {
        ssa += expf(a * A[j * DD + tid] * INV_TAU);
        ssr += expf(a * R[j * DD + tid] * INV_TAU);
    }
    const float Fn = (ssa - expf(a * a * INV_TAU)) + (ssr - fp) + 2.0f * (KK - 1) * fp;
    float l = logf(Fn + EPSL) - lfp;

    #pragma unroll
    for (int i = 1; i < 64; i <<= 1) l += __shfl_xor(l, i, 64);
    __shared__ float red[4];
    const int wid = tid >> 6, lane = tid & 63;
    if (lane == 0) red[wid] = l;
    __syncthreads();
    if (tid == 0) lossk[k] = (red[0] + red[1] + red[2] + red[3]) * (1.0f / DD);
}

__global__ void final_kernel(const float* __restrict__ lossk, float* __restrict__ out)
{
    float v = lossk[threadIdx.x];
    #pragma unroll
    for (int i = 1; i < 64; i <<= 1) v += __shfl_xor(v, i, 64);
    if (threadIdx.x == 0) out[0] = v;
}

extern "C" void kernel_launch(void* const* d_in, const int* in_sizes, int n_in,
                              void* d_out, int out_size, void* d_ws, size_t ws_size,
                              hipStream_t stream)
{
    const float* fa = (const float*)d_in[0];
    const float* fr = (const float*)d_in[1];
    const int* la = (const int*)d_in[2];
    const int* lr = (const int*)d_in[3];
    float* ws = (float*)d_ws;
    float* out = (float*)d_out;
    const int N = in_sizes[2];

    float* P = ws;                                  // [2][GX][K*D]
    float* C = P + 2L * GX * KK * DD;               // [2][GX][K]
    float* AR = C + 2L * GX * KK;                   // [2][K*D]
    float* lossk = AR + 2L * KK * DD;               // [K]

    seg_partial_kernel<<<dim3(GX, 2), 512, 0, stream>>>(fa, fr, la, lr, P, C, N);
    proto_norm_kernel<<<dim3(KK, 2), 256, 0, stream>>>(P, C, AR, GX);
    loss_kernel<<<KK, 256, 0, stream>>>(AR, lossk);
    final_kernel<<<1, 64, 0, stream>>>(lossk, out);
}

// Round 8
// 117.447 us; speedup vs baseline: 1.0641x; 1.0641x over previous
//
#include <hip/hip_runtime.h>
#include <math.h>

#define KK 64
#define DD 256
#define GX 256        // blocks per feature; grid = 512 = 2 blocks/CU
#define CH 16         // rows per MFMA chunk (K of 32x32x16)
#define MAXCHUNK 512  // max rows per block (N <= GX*MAXCHUNK)
#define INV_TAU 2.0f
#define EPSL 1e-8f

typedef unsigned int u32;
typedef __attribute__((ext_vector_type(4))) u32 u32x4;
typedef __attribute__((ext_vector_type(8))) short s16x8;
typedef __attribute__((ext_vector_type(16))) float f32x16;

// round-to-nearest-even f32 -> bf16 bit pattern
__device__ __forceinline__ u32 f2bf(float f) {
    u32 u = __builtin_bit_cast(u32, f);
    return (u + 0x7FFFu + ((u >> 16) & 1u)) >> 16;
}

// ws float layout:
// P : [2][GX][K*D]   per-block partial sums (33.5 MB)
// C : [2][GX][K]     per-block partial counts
// AR: [2][K*D]       normalized prototypes
// lossk: [K]

__global__ __launch_bounds__(512, 4) void seg_mfma_kernel(
    const float* __restrict__ fa, const float* __restrict__ fr,
    const int* __restrict__ la, const int* __restrict__ lr,
    float* __restrict__ P, float* __restrict__ C, int N)
{
    __shared__ int lbl[MAXCHUNK];
    __shared__ int cnt[KK];

    const int tid = threadIdx.x;
    const int g = blockIdx.x, f = blockIdx.y;
    const float* __restrict__ feat = f ? fr : fa;
    const int* __restrict__ label = f ? lr : la;

    if (tid < KK) cnt[tid] = 0;

    const int chunkR = (N + GX - 1) / GX;          // 391 for N=100000
    const int n0 = g * chunkR;
    int rows = min(N, n0 + chunkR) - n0;
    if (rows < 0) rows = 0;

    __syncthreads();
    for (int i = tid; i < rows; i += 512) lbl[i] = label[n0 + i];
    __syncthreads();
    for (int i = tid; i < rows; i += 512) atomicAdd(&cnt[lbl[i]], 1); // off hot path

    const int w = tid >> 6, lane = tid & 63;
    const int half = lane >> 5;        // K half-group (rows half*8 .. half*8+7)
    const int nn = lane & 31;          // col within group / class within group
    const int col0 = w * 32;           // wave owns 32 columns

    // D = onehot(32x16) * F(16x32) accumulated; two class-groups (0-31, 32-63)
    f32x16 acc0 = {0.0f}, acc1 = {0.0f};

    const int nfull = rows / CH;

    // plain coalesced loads: lane reads F[n0 + t*16 + half*8 + j][col0+nn]
    // each dword inst fetches 2 x 128B fully-used cache lines
    #define LOADF(dst, t)                                                       \
    do {                                                                        \
        const float* bp_ = feat + (size_t)(n0 + (t) * CH + half * 8) * DD + col0 + nn; \
        _Pragma("unroll")                                                       \
        for (int j_ = 0; j_ < 8; ++j_) dst[j_] = bp_[j_ * DD];                  \
    } while (0)

    #define DO_CHUNK(vc, lv)                                                    \
    do {                                                                        \
        u32 a0p[4], a1p[4], bpk[4];                                             \
        _Pragma("unroll")                                                       \
        for (int p_ = 0; p_ < 4; ++p_) {                                        \
            const int j0_ = 2 * p_, j1_ = 2 * p_ + 1;                           \
            a0p[p_] = ((lv[j0_] == nn)      ? 0x3F80u : 0u) |                   \
                      ((lv[j1_] == nn)      ? 0x3F800000u : 0u);                \
            a1p[p_] = ((lv[j0_] == nn + 32) ? 0x3F80u : 0u) |                   \
                      ((lv[j1_] == nn + 32) ? 0x3F800000u : 0u);                \
            bpk[p_] = f2bf(vc[j0_]) | (f2bf(vc[j1_]) << 16);                    \
        }                                                                       \
        const s16x8 A0 = __builtin_bit_cast(s16x8, (u32x4){a0p[0], a0p[1], a0p[2], a0p[3]}); \
        const s16x8 A1 = __builtin_bit_cast(s16x8, (u32x4){a1p[0], a1p[1], a1p[2], a1p[3]}); \
        const s16x8 Bf = __builtin_bit_cast(s16x8, (u32x4){bpk[0], bpk[1], bpk[2], bpk[3]}); \
        acc0 = __builtin_amdgcn_mfma_f32_32x32x16_bf16(A0, Bf, acc0, 0, 0, 0);  \
        acc1 = __builtin_amdgcn_mfma_f32_32x32x16_bf16(A1, Bf, acc1, 0, 0, 0);  \
    } while (0)

    float cur[8], nxt[8];
    if (nfull > 0) LOADF(cur, 0);
    for (int t = 0; t < nfull; ++t) {
        if (t + 1 < nfull) LOADF(nxt, t + 1);     // depth-1 register prefetch
        int lv[8];
        const int r0 = t * CH + half * 8;
        #pragma unroll
        for (int j = 0; j < 8; ++j) lv[j] = lbl[r0 + j];
        DO_CHUNK(cur, lv);
        #pragma unroll
        for (int j = 0; j < 8; ++j) cur[j] = nxt[j];
    }
    // tail chunk (rows % 16), clamped
    if (nfull * CH < rows) {
        const int r0 = nfull * CH + half * 8;
        float tv[8];
        int lv[8];
        #pragma unroll
        for (int j = 0; j < 8; ++j) {
            const int rr = r0 + j;
            lv[j] = (rr < rows) ? lbl[rr] : -1;                       // no class match
            tv[j] = feat[(size_t)(n0 + ((rr < rows) ? rr : 0)) * DD + col0 + nn];
        }
        DO_CHUNK(tv, lv);
    }
    #undef LOADF
    #undef DO_CHUNK

    // epilogue: D layout (HW-verified): col = lane&31, class = (rg&3)+8*(rg>>2)+4*half
    float* dstb = P + ((size_t)f * GX + g) * (KK * DD);
    #pragma unroll
    for (int rg = 0; rg < 16; ++rg) {
        const int cls = (rg & 3) + 8 * (rg >> 2) + 4 * half;
        dstb[(size_t)cls * DD + col0 + nn] = acc0[rg];
        dstb[(size_t)(cls + 32) * DD + col0 + nn] = acc1[rg];
    }
    __syncthreads();    // all waves' cnt atomics done
    if (tid < KK) C[((size_t)f * GX + g) * KK + tid] = (float)cnt[tid];
}

__global__ __launch_bounds__(256) void proto_norm_kernel(
    const float* __restrict__ P, const float* __restrict__ C,
    float* __restrict__ AR, int G)
{
    const int k = blockIdx.x, f = blockIdx.y, tid = threadIdx.x;
    const float* base = P + (size_t)f * G * (KK * DD) + (size_t)k * DD + tid;

    float s = 0.0f;
    int g = 0;
    for (; g + 8 <= G; g += 8) {
        float v[8];
        #pragma unroll
        for (int u = 0; u < 8; ++u) v[u] = base[(size_t)(g + u) * (KK * DD)];
        #pragma unroll
        for (int u = 0; u < 8; ++u) s += v[u];
    }
    for (; g < G; ++g) s += base[(size_t)g * (KK * DD)];

    float c = 0.0f;
    const float* cb = C + (size_t)f * G * KK + k;
    for (int g2 = 0; g2 < G; ++g2) c += cb[(size_t)g2 * KK];

    const float m = s / c;
    float sq = m * m;
    #pragma unroll
    for (int i = 1; i < 64; i <<= 1) sq += __shfl_xor(sq, i, 64);
    __shared__ float red[4];
    const int wid = tid >> 6, lane = tid & 63;
    if (lane == 0) red[wid] = sq;
    __syncthreads();
    const float nrm = red[0] + red[1] + red[2] + red[3];
    AR[(size_t)f * KK * DD + (size_t)k * DD + tid] = m / fmaxf(sqrtf(nrm), 1e-12f);
}

__global__ __launch_bounds__(256) void loss_kernel(const float* __restrict__ AR,
                                                   float* __restrict__ lossk)
{
    const float* A = AR;
    const float* R = AR + KK * DD;
    const int k = blockIdx.x, tid = threadIdx.x;

    const float a = A[k * DD + tid];
    const float r = R[k * DD + tid];
    const float lfp = a * r * INV_TAU;
    const float fp = expf(lfp);
    float ssa = 0.0f, ssr = 0.0f;
    #pragma unroll 8
    for (int j = 0; j < KK; ++j) {
        ssa += expf(a * A[j * DD + tid] * INV_TAU);
        ssr += expf(a * R[j * DD + tid] * INV_TAU);
    }
    const float Fn = (ssa - expf(a * a * INV_TAU)) + (ssr - fp) + 2.0f * (KK - 1) * fp;
    float l = logf(Fn + EPSL) - lfp;

    #pragma unroll
    for (int i = 1; i < 64; i <<= 1) l += __shfl_xor(l, i, 64);
    __shared__ float red[4];
    const int wid = tid >> 6, lane = tid & 63;
    if (lane == 0) red[wid] = l;
    __syncthreads();
    if (tid == 0) lossk[k] = (red[0] + red[1] + red[2] + red[3]) * (1.0f / DD);
}

__global__ void final_kernel(const float* __restrict__ lossk, float* __restrict__ out)
{
    float v = lossk[threadIdx.x];
    #pragma unroll
    for (int i = 1; i < 64; i <<= 1) v += __shfl_xor(v, i, 64);
    if (threadIdx.x == 0) out[0] = v;
}

extern "C" void kernel_launch(void* const* d_in, const int* in_sizes, int n_in,
                              void* d_out, int out_size, void* d_ws, size_t ws_size,
                              hipStream_t stream)
{
    const float* fa = (const float*)d_in[0];
    const float* fr = (const float*)d_in[1];
    const int* la = (const int*)d_in[2];
    const int* lr = (const int*)d_in[3];
    float* ws = (float*)d_ws;
    float* out = (float*)d_out;
    const int N = in_sizes[2];

    float* P = ws;                                  // [2][GX][K*D]
    float* C = P + 2L * GX * KK * DD;               // [2][GX][K]
    float* AR = C + 2L * GX * KK;                   // [2][K*D]
    float* lossk = AR + 2L * KK * DD;               // [K]

    seg_mfma_kernel<<<dim3(GX, 2), 512, 0, stream>>>(fa, fr, la, lr, P, C, N);
    proto_norm_kernel<<<dim3(KK, 2), 256, 0, stream>>>(P, C, AR, GX);
    loss_kernel<<<KK, 256, 0, stream>>>(AR, lossk);
    final_kernel<<<1, 64, 0, stream>>>(lossk, out);
}